// Round 7
// baseline (299.108 us; speedup 1.0000x reference)
//
#include <hip/hip_runtime.h>
#include <math.h>

#define S_LEN 512
#define BATCH 256
#define NTAG  128
#define EMSTRIDE (BATCH * NTAG)  /* floats per time step */

typedef float f32x4 __attribute__((ext_vector_type(4)));
typedef float f32x2 __attribute__((ext_vector_type(2)));

// state layout: pad 4 floats per 32 -> 16 owner chunks alias banks only 2-way (free)
__device__ __forceinline__ int slotf(int k) { return k + ((k >> 5) << 2); }
__device__ __forceinline__ f32x2 lo2(f32x4 v){ f32x2 r; r[0]=v[0]; r[1]=v[1]; return r; }
__device__ __forceinline__ f32x2 hi2(f32x4 v){ f32x2 r; r[0]=v[2]; r[1]=v[3]; return r; }
__device__ __forceinline__ f32x2 pmax2(f32x2 a, f32x2 b){ f32x2 r; r[0]=fmaxf(a[0],b[0]); r[1]=fmaxf(a[1],b[1]); return r; }
__device__ __forceinline__ f32x2 fma2(f32x2 a, f32x2 b, f32x2 c){ f32x2 r; r[0]=__builtin_fmaf(a[0],b[0],c[0]); r[1]=__builtin_fmaf(a[1],b[1],c[1]); return r; }

// DPP lane ops (all VALU — no LDS pipe)
#define DPP_XOR1(x) __int_as_float(__builtin_amdgcn_mov_dpp(__float_as_int(x), 0xB1, 0xF, 0xF, false))
#define DPP_XOR2(x) __int_as_float(__builtin_amdgcn_mov_dpp(__float_as_int(x), 0x4E, 0xF, 0xF, false))
#define ROR4f(x)    __int_as_float(__builtin_amdgcn_mov_dpp(__float_as_int(x), 0x124, 0xF, 0xF, false))
#define ROR8f(x)    __int_as_float(__builtin_amdgcn_mov_dpp(__float_as_int(x), 0x128, 0xF, 0xF, false))

// Raw barrier: drain LDS only (NOT vmcnt) so global prefetch stays in flight.
#define BAR() do {                                       \
    asm volatile("s_waitcnt lgkmcnt(0)" ::: "memory");   \
    __builtin_amdgcn_s_barrier();                        \
    __builtin_amdgcn_sched_barrier(0);                   \
  } while (0)

// select-merge ladder: 4 row-accs across 16 owner lanes -> per-lane total of
// row 4q+(o&3). xor1/xor2 via quad_perm, bits 2,3 via row_ror (same-row adds).
#define MERGE_SUM(s0,s1,s2,s3,OUT) {                          \
  float _ma = b0 ? (s1) : (s0), _mb = b0 ? (s0) : (s1);       \
  float _m0 = _ma + DPP_XOR1(_mb);                            \
  float _mc = b0 ? (s3) : (s2), _md = b0 ? (s2) : (s3);       \
  float _m1 = _mc + DPP_XOR1(_md);                            \
  float _me = b1 ? _m1 : _m0, _mf = b1 ? _m0 : _m1;           \
  float _g = _me + DPP_XOR2(_mf);                             \
  _g += ROR4f(_g); _g += ROR8f(_g);                           \
  OUT = _g; }

#define MERGE_MAX(s0,s1,s2,s3,OUT) {                          \
  float _ma = b0 ? (s1) : (s0), _mb = b0 ? (s0) : (s1);       \
  float _m0 = fmaxf(_ma, DPP_XOR1(_mb));                      \
  float _mc = b0 ? (s3) : (s2), _md = b0 ? (s2) : (s3);       \
  float _m1 = fmaxf(_mc, DPP_XOR1(_md));                      \
  float _me = b1 ? _m1 : _m0, _mf = b1 ? _m0 : _m1;           \
  float _g = fmaxf(_me, DPP_XOR2(_mf));                       \
  _g = fmaxf(_g, ROR4f(_g)); _g = fmaxf(_g, ROR8f(_g));       \
  OUT = _g; }

// ---------------------------------------------------------------------------
// One block per batch (grid=256, 512 threads): all four recurrence chains
// (fwd-left, vit-left, fwd-right, vit-right; meet at sm=(len-1)>>1) run in
// lockstep between shared barriers — 4 independent dep chains per thread hide
// each other's latency; exactly 1 block/CU so no inter-block contention.
// Thread map: o=tid&15 owns k in [8o,8o+8); q=tid>>4 owns rows 4q..4q+3.
// ---------------------------------------------------------------------------
__global__ __launch_bounds__(512, 1)
void crf_fused_kernel(const float* __restrict__ emis,
                      const float* __restrict__ mask,
                      const int* __restrict__ tags,
                      const float* __restrict__ trans,
                      const float* __restrict__ startt,
                      const float* __restrict__ stopt,
                      float* __restrict__ out)
{
  const int b    = blockIdx.x;
  const int tid  = threadIdx.x;
  const int lane = tid & 63;
  const int wid  = tid >> 6;
  const int o    = tid & 15;
  const int q    = tid >> 4;               // 0..31
  const bool b0  = (o & 1) != 0;
  const bool b1  = (o & 2) != 0;
  const bool o4  = (o < 4);
  const int rmine = 4 * q + (o & 3);       // my output row (and em row)
  const int cb    = 8 * o + ((o >> 2) << 2);   // slotf(8o)
  const int wslot = slotf(rmine);

  __shared__ __align__(16) float sb[4][2][144];  // 0=FL 1=VL 2=FR 3=VR
  __shared__ float red[8];

  // ---- len = sum_s mask[s,b] (mask monotone) ----
  int len;
  {
    float mv = mask[(size_t)tid * BATCH + b];
#pragma unroll
    for (int d = 1; d <= 32; d <<= 1) mv += __shfl_xor(mv, d);
    if (lane == 0) red[wid] = mv;
    __syncthreads();
    float ls = 0.f;
#pragma unroll
    for (int w = 0; w < 8; ++w) ls += red[w];
    len = (int)(ls + 0.5f);
    len = __builtin_amdgcn_readfirstlane(len);
  }
  const int sm     = (len - 1) >> 1;
  const int nsteps = len - 1 - sm;         // right/backward step count (>= sm)
  __syncthreads();

  // ---- init the four states ----
  if (tid < 128) {
    int k = tid, sk = slotf(k);
    float em0 = emis[(size_t)b * NTAG + k];
    float st  = startt[k];
    float sp  = stopt[k];
    float emL = emis[((size_t)(len - 1) * BATCH + b) * NTAG + k];
    float l0  = st + em0;
    float r0  = (nsteps > 0) ? sp + emL : sp;
    sb[0][0][sk] = __expf(l0);
    sb[1][0][sk] = l0;
    sb[2][0][sk] = __expf(r0);
    sb[3][0][sk] = r0;
  }

  // ---- matrices in registers: rows 4q..4q+3 x k [8o,8o+8) ----
  f32x2 EL[16], TL[16], ER[16], TR[16];
  {
    const float* trL = trans + (size_t)(4 * q) * NTAG + 8 * o;
#pragma unroll
    for (int r = 0; r < 4; ++r) {
      f32x4 tA = *(const f32x4*)(trL + (size_t)r * NTAG);
      f32x4 tB = *(const f32x4*)(trL + (size_t)r * NTAG + 4);
      TL[r*4+0] = lo2(tA); TL[r*4+1] = hi2(tA);
      TL[r*4+2] = lo2(tB); TL[r*4+3] = hi2(tB);
#pragma unroll
      for (int p = 0; p < 4; ++p) {
        f32x2 t = TL[r*4+p], e;
        e[0] = __expf(t[0]); e[1] = __expf(t[1]);
        EL[r*4+p] = e;
      }
    }
    const float* trR = trans + (size_t)(8 * o) * NTAG + 4 * q;
#pragma unroll
    for (int p = 0; p < 4; ++p) {
#pragma unroll
      for (int r = 0; r < 4; ++r) {
        float x0 = trR[(size_t)(2*p)   * NTAG + r];
        float x1 = trR[(size_t)(2*p+1) * NTAG + r];
        f32x2 t; t[0] = x0; t[1] = x1;
        TR[r*4+p] = t;
        f32x2 e; e[0] = __expf(x0); e[1] = __expf(x1);
        ER[r*4+p] = e;
      }
    }
  }

  // ---- emission streams (up for L at s=i+1, down for R at s=len-2-i) ----
  const float* ebm = emis + (size_t)b * NTAG + rmine;
  float eu0 = ebm[(size_t)1 * EMSTRIDE];
  float eu1 = ebm[(size_t)2 * EMSTRIDE];
  float eu2 = ebm[(size_t)3 * EMSTRIDE];
  float eu3 = ebm[(size_t)4 * EMSTRIDE];
  int td0 = len - 2; td0 = td0 > 0 ? td0 : 0;
  int td1 = len - 3; td1 = td1 > 0 ? td1 : 0;
  int td2 = len - 4; td2 = td2 > 0 ? td2 : 0;
  int td3 = len - 5; td3 = td3 > 0 ? td3 : 0;
  float ed0 = ebm[(size_t)td0 * EMSTRIDE];
  float ed1 = ebm[(size_t)td1 * EMSTRIDE];
  float ed2 = ebm[(size_t)td2 * EMSTRIDE];
  float ed3 = ebm[(size_t)td3 * EMSTRIDE];

  int EwL = 0, EwR = 0;
  __syncthreads();

#define FWD_CORE(ROLE, MAT, P, EXV, RN, EWACC) {                               \
    const float* _rb = &sb[ROLE][P][cb];                                       \
    f32x4 _wA = *(const f32x4*)_rb;                                            \
    f32x4 _wB = *(const f32x4*)(_rb + 4);                                      \
    f32x2 _p0 = lo2(_wA), _p1 = hi2(_wA), _p2 = lo2(_wB), _p3 = hi2(_wB);      \
    f32x2 _a0 = MAT[0]*_p0;  _a0 = fma2(MAT[1],_p1,_a0);                       \
    _a0 = fma2(MAT[2],_p2,_a0);  _a0 = fma2(MAT[3],_p3,_a0);                   \
    f32x2 _a1 = MAT[4]*_p0;  _a1 = fma2(MAT[5],_p1,_a1);                       \
    _a1 = fma2(MAT[6],_p2,_a1);  _a1 = fma2(MAT[7],_p3,_a1);                   \
    f32x2 _a2 = MAT[8]*_p0;  _a2 = fma2(MAT[9],_p1,_a2);                       \
    _a2 = fma2(MAT[10],_p2,_a2); _a2 = fma2(MAT[11],_p3,_a2);                  \
    f32x2 _a3 = MAT[12]*_p0; _a3 = fma2(MAT[13],_p1,_a3);                      \
    _a3 = fma2(MAT[14],_p2,_a3); _a3 = fma2(MAT[15],_p3,_a3);                  \
    float _s0=_a0[0]+_a0[1], _s1=_a1[0]+_a1[1];                                \
    float _s2=_a2[0]+_a2[1], _s3=_a3[0]+_a3[1];                                \
    float _f; MERGE_SUM(_s0,_s1,_s2,_s3,_f);                                   \
    float _uf;                                                                 \
    if (RN) {                                                                  \
      f32x2 _r2 = pmax2(pmax2(_p0,_p1), pmax2(_p2,_p3));                       \
      float _rw = fmaxf(_r2[0],_r2[1]);                                        \
      _rw = fmaxf(_rw, DPP_XOR1(_rw)); _rw = fmaxf(_rw, DPP_XOR2(_rw));        \
      _rw = fmaxf(_rw, ROR4f(_rw));    _rw = fmaxf(_rw, ROR8f(_rw));           \
      int _ew = (int)((__float_as_uint(_rw) >> 23) & 0xFF) - 126;              \
      EWACC += _ew;                                                            \
      float _swc = __uint_as_float((unsigned)(127 - _ew) << 23);               \
      _uf = (EXV) * _f * _swc;                                                 \
    } else {                                                                   \
      _uf = (EXV) * _f;                                                        \
    }                                                                          \
    if (o4) sb[ROLE][(P)^1][wslot] = _uf; }

#define VIT_CORE(ROLE, MAT, P, EMV, LASTF) {                                   \
    const float* _rb = &sb[ROLE][P][cb];                                       \
    f32x4 _wA = *(const f32x4*)_rb;                                            \
    f32x4 _wB = *(const f32x4*)(_rb + 4);                                      \
    f32x2 _p0 = lo2(_wA), _p1 = hi2(_wA), _p2 = lo2(_wB), _p3 = hi2(_wB);      \
    f32x2 _m0 = pmax2(_p0+MAT[0],  _p1+MAT[1]);                                \
    _m0 = pmax2(_m0, pmax2(_p2+MAT[2],  _p3+MAT[3]));                          \
    f32x2 _m1 = pmax2(_p0+MAT[4],  _p1+MAT[5]);                                \
    _m1 = pmax2(_m1, pmax2(_p2+MAT[6],  _p3+MAT[7]));                          \
    f32x2 _m2 = pmax2(_p0+MAT[8],  _p1+MAT[9]);                                \
    _m2 = pmax2(_m2, pmax2(_p2+MAT[10], _p3+MAT[11]));                         \
    f32x2 _m3 = pmax2(_p0+MAT[12], _p1+MAT[13]);                               \
    _m3 = pmax2(_m3, pmax2(_p2+MAT[14], _p3+MAT[15]));                         \
    float _s0=fmaxf(_m0[0],_m0[1]), _s1=fmaxf(_m1[0],_m1[1]);                  \
    float _s2=fmaxf(_m2[0],_m2[1]), _s3=fmaxf(_m3[0],_m3[1]);                  \
    float _f; MERGE_MAX(_s0,_s1,_s2,_s3,_f);                                   \
    float _uv = (LASTF) ? _f : _f + (EMV);                                     \
    if (o4) sb[ROLE][(P)^1][wslot] = _uv; }

#define SUBSTEP(U, EU, ED, RN) {                                               \
    const int _ii = gbase + (U);                                               \
    if (_ii >= nsteps) goto epi;                                               \
    const bool _lastR = (_ii == nsteps - 1);                                   \
    if (_ii < sm) {                                                            \
      float _exu = __expf(EU);                                                 \
      FWD_CORE(0, EL, (U)&1, _exu, RN, EwL)                                    \
      VIT_CORE(1, TL, (U)&1, EU, false)                                        \
    }                                                                          \
    {                                                                          \
      float _exd = _lastR ? 1.0f : __expf(ED);                                 \
      FWD_CORE(2, ER, (U)&1, _exd, RN, EwR)                                    \
      VIT_CORE(3, TR, (U)&1, ED, _lastR)                                       \
    }                                                                          \
    BAR(); }

  for (int gbase = 0; gbase < S_LEN; gbase += 4) {
    int cu0 = gbase + 5 < S_LEN ? gbase + 5 : S_LEN - 1;
    int cu1 = gbase + 6 < S_LEN ? gbase + 6 : S_LEN - 1;
    int cu2 = gbase + 7 < S_LEN ? gbase + 7 : S_LEN - 1;
    int cu3 = gbase + 8 < S_LEN ? gbase + 8 : S_LEN - 1;
    int cd0 = len - 6 - gbase; cd0 = cd0 > 0 ? cd0 : 0;
    int cd1 = len - 7 - gbase; cd1 = cd1 > 0 ? cd1 : 0;
    int cd2 = len - 8 - gbase; cd2 = cd2 > 0 ? cd2 : 0;
    int cd3 = len - 9 - gbase; cd3 = cd3 > 0 ? cd3 : 0;
    float nu0 = ebm[(size_t)cu0 * EMSTRIDE];
    float nu1 = ebm[(size_t)cu1 * EMSTRIDE];
    float nu2 = ebm[(size_t)cu2 * EMSTRIDE];
    float nu3 = ebm[(size_t)cu3 * EMSTRIDE];
    float nd0 = ebm[(size_t)cd0 * EMSTRIDE];
    float nd1 = ebm[(size_t)cd1 * EMSTRIDE];
    float nd2 = ebm[(size_t)cd2 * EMSTRIDE];
    float nd3 = ebm[(size_t)cd3 * EMSTRIDE];

    SUBSTEP(0, eu0, ed0, 0)
    SUBSTEP(1, eu1, ed1, 0)
    SUBSTEP(2, eu2, ed2, 0)
    SUBSTEP(3, eu3, ed3, 1)   // renorm fwd chains every 4th step

    eu0 = nu0; eu1 = nu1; eu2 = nu2; eu3 = nu3;
    ed0 = nd0; ed1 = nd1; ed2 = nd2; ed3 = nd3;
  }

epi: ;
  __syncthreads();
  // ---- combine: total = (EwL+EwR)ln2 + log(sum_k WL*WR); best = max(VL+VR)
  {
    const int finL = sm & 1, finR = nsteps & 1;
    float tsum = 0.f, tmax = -3.0e38f;
    if (tid < 128) {
      int sk = slotf(tid);
      float wl = sb[0][finL][sk], vl = sb[1][finL][sk];
      float wr = sb[2][finR][sk], vr = sb[3][finR][sk];
      tsum = wl * wr;
      tmax = vl + vr;
    }
#pragma unroll
    for (int d = 1; d <= 32; d <<= 1) {
      tsum += __shfl_xor(tsum, d);
      tmax  = fmaxf(tmax, __shfl_xor(tmax, d));
    }
    if (tid == 0)  { red[0] = tsum; red[2] = tmax; }
    if (tid == 64) { red[1] = tsum; red[3] = tmax; }
    __syncthreads();
    if (tid == 0) {
      const double LN2 = 0.6931471805599453;
      float S = red[0] + red[1];
      float M = fmaxf(red[2], red[3]);
      out[1 + BATCH + b]     = (float)((double)(EwL + EwR) * LN2 + (double)__logf(S));
      out[1 + 2 * BATCH + b] = M;
    }
  }
  __syncthreads();

  // ---- gold path score (s = tid; mask monotone, prev tag = tags[s-1]) ----
  {
    float m  = mask[(size_t)tid * BATCH + b];
    int  cur = tags[(size_t)tid * BATCH + b];
    float part;
    if (tid == 0) {
      part = startt[cur] + emis[(size_t)b * NTAG + cur] * m;
    } else {
      int prev = tags[(size_t)(tid - 1) * BATCH + b];
      part = m * (trans[(size_t)prev * NTAG + cur] +
                  emis[((size_t)tid * BATCH + b) * NTAG + cur]);
    }
#pragma unroll
    for (int d = 1; d <= 32; d <<= 1) part += __shfl_xor(part, d);
    if (lane == 0) red[wid] = part;
    __syncthreads();
    if (tid == 0) {
      float rps = 0.f;
#pragma unroll
      for (int w = 0; w < 8; ++w) rps += red[w];
      int pf = tags[(size_t)(len - 1) * BATCH + b];
      out[1 + b] = rps + stopt[pf];
    }
  }
}

// ---------------------------------------------------------------------------
// loss = mean(total_score - real_path_score)
// ---------------------------------------------------------------------------
__global__ __launch_bounds__(256, 1)
void crf_loss_kernel(float* __restrict__ out)
{
  const int tid = threadIdx.x;
  float dft = out[1 + BATCH + tid] - out[1 + tid];
#pragma unroll
  for (int d = 1; d <= 32; d <<= 1) dft += __shfl_xor(dft, d);
  __shared__ float rs[4];
  const int lane = tid & 63, wid = tid >> 6;
  if (lane == 0) rs[wid] = dft;
  __syncthreads();
  if (tid == 0)
    out[0] = ((rs[0] + rs[1]) + (rs[2] + rs[3])) * (1.0f / BATCH);
}

extern "C" void kernel_launch(void* const* d_in, const int* in_sizes, int n_in,
                              void* d_out, int out_size, void* d_ws, size_t ws_size,
                              hipStream_t stream)
{
  const float* emis   = (const float*)d_in[0];
  const float* mask   = (const float*)d_in[1];
  const int*   tags   = (const int*)d_in[2];
  const float* trans  = (const float*)d_in[3];
  const float* startt = (const float*)d_in[4];
  const float* stopt  = (const float*)d_in[5];
  float* out = (float*)d_out;

  crf_fused_kernel<<<BATCH, 512, 0, stream>>>(emis, mask, tags, trans,
                                              startt, stopt, out);
  crf_loss_kernel<<<1, 256, 0, stream>>>(out);
}

// Round 8
// 214.550 us; speedup vs baseline: 1.3941x; 1.3941x over previous
//
#include <hip/hip_runtime.h>
#include <math.h>

#define S_LEN 512
#define BATCH 256
#define NTAG  128
#define EMSTRIDE (BATCH * NTAG)  /* floats per time step */

typedef float f32x4 __attribute__((ext_vector_type(4)));
typedef float f32x2 __attribute__((ext_vector_type(2)));

// swizzled LDS float index: pad 8 floats after every 32 -> the 4 k-quarters'
// broadcast addresses land on disjoint bank quads. (R3/R4-proven, 0 conflicts)
__device__ __forceinline__ int swz(int k) { return k + ((k >> 5) << 3); }

__device__ __forceinline__ f32x2 lo2(f32x4 v){ f32x2 r; r[0]=v[0]; r[1]=v[1]; return r; }
__device__ __forceinline__ f32x2 hi2(f32x4 v){ f32x2 r; r[0]=v[2]; r[1]=v[3]; return r; }
__device__ __forceinline__ f32x2 pmax2(f32x2 a, f32x2 b){ f32x2 r; r[0]=fmaxf(a[0],b[0]); r[1]=fmaxf(a[1],b[1]); return r; }
__device__ __forceinline__ f32x2 fma2(f32x2 a, f32x2 b, f32x2 c){ f32x2 r; r[0]=__builtin_fmaf(a[0],b[0],c[0]); r[1]=__builtin_fmaf(a[1],b[1],c[1]); return r; }
__device__ __forceinline__ float max3f(float a, float b, float c){ return fmaxf(fmaxf(a,b),c); } // -> v_max3_f32

// DPP quad-perm butterfly (intra-quad, VALU-speed, no LDS pipe)
#define DPP_XOR1(x) __int_as_float(__builtin_amdgcn_mov_dpp(__float_as_int(x), 0xB1, 0xF, 0xF, false))
#define DPP_XOR2(x) __int_as_float(__builtin_amdgcn_mov_dpp(__float_as_int(x), 0x4E, 0xF, 0xF, false))

// Raw barrier: drain LDS only (NOT vmcnt) so global prefetch stays in flight.
#define BAR() do {                                       \
    asm volatile("s_waitcnt lgkmcnt(0)" ::: "memory");   \
    __builtin_amdgcn_s_barrier();                        \
    __builtin_amdgcn_sched_barrier(0);                   \
  } while (0)

// ---------------------------------------------------------------------------
// Fat kernel, 512 threads/block, grid = 5*BATCH:
//   role = blk>>8: 0=fwd-left, 1=fwd-right(backward), 2=vit-left,
//                  3=vit-right(backward), 4=gold.  b = blk&255.
// Meet at sm=(len-1)>>1; combine kernel does the dot/max merge (R5-validated).
// Recurrence thread map (R4-proven): j = tid>>2 (one output row), h = tid&3
// (k-quarter, 32 floats read/step). Inner loops packed: v_pk_fma_f32 (fwd),
// v_pk_add_f32 + v_max3_f32 (vit).
// ---------------------------------------------------------------------------
__global__ __launch_bounds__(512, 1)
void crf_fat_kernel(const float* __restrict__ emis,
                    const float* __restrict__ mask,
                    const int* __restrict__ tags,
                    const float* __restrict__ trans,
                    const float* __restrict__ startt,
                    const float* __restrict__ stopt,
                    float* __restrict__ ws,
                    int* __restrict__ ewbuf,
                    float* __restrict__ out)
{
  const int blk  = blockIdx.x;
  const int tid  = threadIdx.x;
  const int role = blk >> 8;
  const int b    = blk & 255;
  const int lane = tid & 63;
  const int wid  = tid >> 6;

  __shared__ __align__(16) float sbuf[2][160];
  __shared__ float red[16];

  // ---------------- gold role ----------------
  if (role == 4) {
    const int s = tid;
    float m  = mask[(size_t)s * BATCH + b];
    int  cur = tags[(size_t)s * BATCH + b];
    float part, lenp = m;
    if (s == 0) {
      part = startt[cur] + emis[(size_t)b * NTAG + cur] * m;
    } else {
      int prev = tags[(size_t)(s - 1) * BATCH + b];
      part = m * (trans[(size_t)prev * NTAG + cur] +
                  emis[((size_t)s * BATCH + b) * NTAG + cur]);
    }
#pragma unroll
    for (int d = 1; d <= 32; d <<= 1) {
      part += __shfl_xor(part, d);
      lenp += __shfl_xor(lenp, d);
    }
    if (lane == 0) { red[wid] = part; red[8 + wid] = lenp; }
    __syncthreads();
    if (tid == 0) {
      float rps = 0.f, lf = 0.f;
#pragma unroll
      for (int w = 0; w < 8; ++w) { rps += red[w]; lf += red[8 + w]; }
      int len = (int)(lf + 0.5f);
      int pf  = tags[(size_t)(len - 1) * BATCH + b];
      out[1 + b] = rps + stopt[pf];
    }
    return;
  }

  const int h   = tid & 3;
  const int j   = tid >> 2;          // 0..127
  const int base = 10 * h;           // f32x4 chunk base of my k-quarter

  // ---- len = sum_s mask[s,b] (mask monotone) ----
  int len;
  {
    float mv = mask[(size_t)tid * BATCH + b];
#pragma unroll
    for (int d = 1; d <= 32; d <<= 1) mv += __shfl_xor(mv, d);
    if (lane == 0) red[wid] = mv;
    __syncthreads();
    float ls = 0.f;
#pragma unroll
    for (int w = 0; w < 8; ++w) ls += red[w];
    len = (int)(ls + 0.5f);
    len = __builtin_amdgcn_readfirstlane(len);
  }
  const int sm     = (len - 1) >> 1;
  const int nsteps = len - 1 - sm;   // right/backward step count
  const float* eb  = emis + (size_t)b * NTAG + j;

  if (role == 0) {
    // ========== forward-left (exp space, rows of E, pk_fma) ==========
    f32x2 E2[16];
    {
      const float* tr = trans + (size_t)j * NTAG + 32 * h;
#pragma unroll
      for (int c = 0; c < 8; ++c) {
        f32x4 t = *(const f32x4*)(tr + 4 * c);
        f32x2 a, bb;
        a[0] = __expf(t[0]);  a[1] = __expf(t[1]);
        bb[0] = __expf(t[2]); bb[1] = __expf(t[3]);
        E2[2*c] = a; E2[2*c+1] = bb;
      }
    }
    if (h == 0) sbuf[0][swz(j)] = __expf(startt[j] + eb[0]);
    float e0 = eb[(size_t)1 * EMSTRIDE];
    float e1 = eb[(size_t)2 * EMSTRIDE];
    float e2 = eb[(size_t)3 * EMSTRIDE];
    float e3 = eb[(size_t)4 * EMSTRIDE];
    int Ew = 0, fin = 0;
    __syncthreads();

#define FSTEP(U, EMV, RENORM)                                                 \
  {                                                                           \
    if (g + (U) > sm) { fin = (U) & 1; goto epi_f; }                          \
    const f32x4* wr = (const f32x4*)sbuf[(U) & 1];                            \
    f32x2 a0 = {0.f,0.f}, a1 = {0.f,0.f}, r2 = {0.f,0.f};                     \
    _Pragma("unroll")                                                         \
    for (int c = 0; c < 8; ++c) {                                             \
      f32x4 w = wr[base + c];                                                 \
      f32x2 wl = lo2(w), wh = hi2(w);                                         \
      a0 = fma2(E2[2*c],   wl, a0);                                           \
      a1 = fma2(E2[2*c+1], wh, a1);                                           \
      if (RENORM) r2 = pmax2(r2, pmax2(wl, wh));                              \
    }                                                                         \
    f32x2 as = a0 + a1;                                                       \
    float sum = as[0] + as[1];                                                \
    sum += DPP_XOR1(sum); sum += DPP_XOR2(sum);                               \
    float ex = __expf(EMV);                                                   \
    float uf;                                                                 \
    if (RENORM) {                                                             \
      float rw = fmaxf(r2[0], r2[1]);                                         \
      rw = fmaxf(rw, DPP_XOR1(rw)); rw = fmaxf(rw, DPP_XOR2(rw));             \
      int ew = (int)((__float_as_uint(rw) >> 23) & 0xFF) - 126;               \
      Ew += ew;                                                               \
      float swc = __uint_as_float((unsigned)(127 - ew) << 23);                \
      uf = ex * sum * swc;                                                    \
    } else {                                                                  \
      uf = ex * sum;                                                          \
    }                                                                         \
    if (h == 0) sbuf[((U) + 1) & 1][swz(j)] = uf;                             \
    BAR();                                                                    \
  }

    for (int g = 1; g < S_LEN; g += 4) {
      int c0 = g + 4 < S_LEN ? g + 4 : S_LEN - 1;
      int c1 = g + 5 < S_LEN ? g + 5 : S_LEN - 1;
      int c2 = g + 6 < S_LEN ? g + 6 : S_LEN - 1;
      int c3 = g + 7 < S_LEN ? g + 7 : S_LEN - 1;
      float n0 = eb[(size_t)c0 * EMSTRIDE];
      float n1 = eb[(size_t)c1 * EMSTRIDE];
      float n2 = eb[(size_t)c2 * EMSTRIDE];
      float n3 = eb[(size_t)c3 * EMSTRIDE];
      FSTEP(0, e0, 0)
      FSTEP(1, e1, 0)
      FSTEP(2, e2, 0)
      FSTEP(3, e3, 1)   // renorm every 4th step (growth < 2^80, fp32-safe)
      e0 = n0; e1 = n1; e2 = n2; e3 = n3;
    }
    fin = 0;
epi_f:
    if (tid < 128) ws[(size_t)b * 512 + tid] = sbuf[fin][swz(tid)];
    if (tid == 0) ewbuf[b] = Ew;
  } else if (role == 1) {
    // ========== forward-right / backward (exp space, columns of E) ==========
    f32x2 E2[16];
    {
      const float* tc = trans + j + (size_t)(32 * h) * NTAG;
#pragma unroll
      for (int q = 0; q < 16; ++q) {
        f32x2 a;
        a[0] = __expf(tc[(size_t)(2*q)     * NTAG]);
        a[1] = __expf(tc[(size_t)(2*q + 1) * NTAG]);
        E2[q] = a;
      }
    }
    if (h == 0) {
      float st = stopt[j];
      sbuf[0][swz(j)] = (nsteps > 0) ? __expf(st + eb[(size_t)(len - 1) * EMSTRIDE])
                                     : __expf(st);
    }
    int s0i = len - 2; s0i = s0i < 0 ? 0 : s0i;
    int s1i = len - 3; s1i = s1i < 0 ? 0 : s1i;
    int s2i = len - 4; s2i = s2i < 0 ? 0 : s2i;
    int s3i = len - 5; s3i = s3i < 0 ? 0 : s3i;
    float e0 = eb[(size_t)s0i * EMSTRIDE];
    float e1 = eb[(size_t)s1i * EMSTRIDE];
    float e2 = eb[(size_t)s2i * EMSTRIDE];
    float e3 = eb[(size_t)s3i * EMSTRIDE];
    int Ew = 0, fin = 0;
    __syncthreads();

#define BSTEP(U, EMV, RENORM)                                                 \
  {                                                                           \
    if (gi + (U) >= nsteps) { fin = (U) & 1; goto epi_b; }                    \
    const f32x4* wr = (const f32x4*)sbuf[(U) & 1];                            \
    f32x2 a0 = {0.f,0.f}, a1 = {0.f,0.f}, r2 = {0.f,0.f};                     \
    _Pragma("unroll")                                                         \
    for (int c = 0; c < 8; ++c) {                                             \
      f32x4 w = wr[base + c];                                                 \
      f32x2 wl = lo2(w), wh = hi2(w);                                         \
      a0 = fma2(E2[2*c],   wl, a0);                                           \
      a1 = fma2(E2[2*c+1], wh, a1);                                           \
      if (RENORM) r2 = pmax2(r2, pmax2(wl, wh));                              \
    }                                                                         \
    f32x2 as = a0 + a1;                                                       \
    float sum = as[0] + as[1];                                                \
    sum += DPP_XOR1(sum); sum += DPP_XOR2(sum);                               \
    float ex  = __expf(EMV);                                                  \
    float exm = (gi + (U) == nsteps - 1) ? 1.0f : ex;                         \
    float uf;                                                                 \
    if (RENORM) {                                                             \
      float rw = fmaxf(r2[0], r2[1]);                                         \
      rw = fmaxf(rw, DPP_XOR1(rw)); rw = fmaxf(rw, DPP_XOR2(rw));             \
      int ew = (int)((__float_as_uint(rw) >> 23) & 0xFF) - 126;               \
      Ew += ew;                                                               \
      float swc = __uint_as_float((unsigned)(127 - ew) << 23);                \
      uf = exm * sum * swc;                                                   \
    } else {                                                                  \
      uf = exm * sum;                                                         \
    }                                                                         \
    if (h == 0) sbuf[((U) + 1) & 1][swz(j)] = uf;                             \
    BAR();                                                                    \
  }

    for (int gi = 0; gi < S_LEN; gi += 4) {
      int c0 = len - 2 - (gi + 4); c0 = c0 < 0 ? 0 : c0;
      int c1 = len - 2 - (gi + 5); c1 = c1 < 0 ? 0 : c1;
      int c2 = len - 2 - (gi + 6); c2 = c2 < 0 ? 0 : c2;
      int c3 = len - 2 - (gi + 7); c3 = c3 < 0 ? 0 : c3;
      float n0 = eb[(size_t)c0 * EMSTRIDE];
      float n1 = eb[(size_t)c1 * EMSTRIDE];
      float n2 = eb[(size_t)c2 * EMSTRIDE];
      float n3 = eb[(size_t)c3 * EMSTRIDE];
      BSTEP(0, e0, 0)
      BSTEP(1, e1, 0)
      BSTEP(2, e2, 0)
      BSTEP(3, e3, 1)
      e0 = n0; e1 = n1; e2 = n2; e3 = n3;
    }
    fin = 0;
epi_b:
    if (tid < 128) ws[(size_t)b * 512 + 128 + tid] = sbuf[fin][swz(tid)];
    if (tid == 0) ewbuf[BATCH + b] = Ew;
  } else if (role == 2) {
    // ========== viterbi-left (log space, rows of T, pk_add + max3) ==========
    f32x2 T2[16];
    {
      const float* tr = trans + (size_t)j * NTAG + 32 * h;
#pragma unroll
      for (int c = 0; c < 8; ++c) {
        f32x4 t = *(const f32x4*)(tr + 4 * c);
        T2[2*c]   = lo2(t);
        T2[2*c+1] = hi2(t);
      }
    }
    if (h == 0) sbuf[0][swz(j)] = startt[j] + eb[0];
    float e0 = eb[(size_t)1 * EMSTRIDE];
    float e1 = eb[(size_t)2 * EMSTRIDE];
    float e2 = eb[(size_t)3 * EMSTRIDE];
    float e3 = eb[(size_t)4 * EMSTRIDE];
    int fin = 0;
    __syncthreads();

#define VSTEP(U, EMV)                                                         \
  {                                                                           \
    if (g + (U) > sm) { fin = (U) & 1; goto epi_v; }                          \
    const f32x4* vr = (const f32x4*)sbuf[(U) & 1];                            \
    float mA = -3.0e38f, mB = -3.0e38f;                                       \
    _Pragma("unroll")                                                         \
    for (int c = 0; c < 8; ++c) {                                             \
      f32x4 v = vr[base + c];                                                 \
      f32x2 x0 = lo2(v) + T2[2*c];                                            \
      f32x2 x1 = hi2(v) + T2[2*c+1];                                          \
      mA = max3f(mA, x0[0], x0[1]);                                           \
      mB = max3f(mB, x1[0], x1[1]);                                           \
    }                                                                         \
    float vm = fmaxf(mA, mB);                                                 \
    vm = fmaxf(vm, DPP_XOR1(vm)); vm = fmaxf(vm, DPP_XOR2(vm));               \
    if (h == 0) sbuf[((U) + 1) & 1][swz(j)] = (EMV) + vm;                     \
    BAR();                                                                    \
  }

    for (int g = 1; g < S_LEN; g += 4) {
      int c0 = g + 4 < S_LEN ? g + 4 : S_LEN - 1;
      int c1 = g + 5 < S_LEN ? g + 5 : S_LEN - 1;
      int c2 = g + 6 < S_LEN ? g + 6 : S_LEN - 1;
      int c3 = g + 7 < S_LEN ? g + 7 : S_LEN - 1;
      float n0 = eb[(size_t)c0 * EMSTRIDE];
      float n1 = eb[(size_t)c1 * EMSTRIDE];
      float n2 = eb[(size_t)c2 * EMSTRIDE];
      float n3 = eb[(size_t)c3 * EMSTRIDE];
      VSTEP(0, e0)
      VSTEP(1, e1)
      VSTEP(2, e2)
      VSTEP(3, e3)
      e0 = n0; e1 = n1; e2 = n2; e3 = n3;
    }
    fin = 0;
epi_v:
    if (tid < 128) ws[(size_t)b * 512 + 256 + tid] = sbuf[fin][swz(tid)];
  } else {
    // ========== viterbi-right / backward (log space, columns of T) ==========
    f32x2 T2[16];
    {
      const float* tc = trans + j + (size_t)(32 * h) * NTAG;
#pragma unroll
      for (int q = 0; q < 16; ++q) {
        f32x2 a;
        a[0] = tc[(size_t)(2*q)     * NTAG];
        a[1] = tc[(size_t)(2*q + 1) * NTAG];
        T2[q] = a;
      }
    }
    if (h == 0) {
      float st = stopt[j];
      sbuf[0][swz(j)] = (nsteps > 0) ? st + eb[(size_t)(len - 1) * EMSTRIDE] : st;
    }
    int s0i = len - 2; s0i = s0i < 0 ? 0 : s0i;
    int s1i = len - 3; s1i = s1i < 0 ? 0 : s1i;
    int s2i = len - 4; s2i = s2i < 0 ? 0 : s2i;
    int s3i = len - 5; s3i = s3i < 0 ? 0 : s3i;
    float e0 = eb[(size_t)s0i * EMSTRIDE];
    float e1 = eb[(size_t)s1i * EMSTRIDE];
    float e2 = eb[(size_t)s2i * EMSTRIDE];
    float e3 = eb[(size_t)s3i * EMSTRIDE];
    int fin = 0;
    __syncthreads();

#define WSTEP(U, EMV)                                                         \
  {                                                                           \
    if (gi + (U) >= nsteps) { fin = (U) & 1; goto epi_w; }                    \
    const f32x4* vr = (const f32x4*)sbuf[(U) & 1];                            \
    float mA = -3.0e38f, mB = -3.0e38f;                                       \
    _Pragma("unroll")                                                         \
    for (int c = 0; c < 8; ++c) {                                             \
      f32x4 v = vr[base + c];                                                 \
      f32x2 x0 = lo2(v) + T2[2*c];                                            \
      f32x2 x1 = hi2(v) + T2[2*c+1];                                          \
      mA = max3f(mA, x0[0], x0[1]);                                           \
      mB = max3f(mB, x1[0], x1[1]);                                           \
    }                                                                         \
    float vm = fmaxf(mA, mB);                                                 \
    vm = fmaxf(vm, DPP_XOR1(vm)); vm = fmaxf(vm, DPP_XOR2(vm));               \
    float uv = (gi + (U) == nsteps - 1) ? vm : vm + (EMV);                    \
    if (h == 0) sbuf[((U) + 1) & 1][swz(j)] = uv;                             \
    BAR();                                                                    \
  }

    for (int gi = 0; gi < S_LEN; gi += 4) {
      int c0 = len - 2 - (gi + 4); c0 = c0 < 0 ? 0 : c0;
      int c1 = len - 2 - (gi + 5); c1 = c1 < 0 ? 0 : c1;
      int c2 = len - 2 - (gi + 6); c2 = c2 < 0 ? 0 : c2;
      int c3 = len - 2 - (gi + 7); c3 = c3 < 0 ? 0 : c3;
      float n0 = eb[(size_t)c0 * EMSTRIDE];
      float n1 = eb[(size_t)c1 * EMSTRIDE];
      float n2 = eb[(size_t)c2 * EMSTRIDE];
      float n3 = eb[(size_t)c3 * EMSTRIDE];
      WSTEP(0, e0)
      WSTEP(1, e1)
      WSTEP(2, e2)
      WSTEP(3, e3)
      e0 = n0; e1 = n1; e2 = n2; e3 = n3;
    }
    fin = 0;
epi_w:
    if (tid < 128) ws[(size_t)b * 512 + 384 + tid] = sbuf[fin][swz(tid)];
  }
}

// ---------------------------------------------------------------------------
// Combine: total = (EwF+EwB)ln2 + log(sum_k WF*WB); best = max_k(VF+VB).
// ---------------------------------------------------------------------------
__global__ __launch_bounds__(128, 1)
void crf_combine_kernel(const float* __restrict__ ws,
                        const int* __restrict__ ewbuf,
                        float* __restrict__ out)
{
  const int b = blockIdx.x, k = threadIdx.x;
  const float* base = ws + (size_t)b * 512;
  float t1 = base[k] * base[128 + k];
  float m1 = base[256 + k] + base[384 + k];
#pragma unroll
  for (int d = 1; d <= 32; d <<= 1) {
    t1 += __shfl_xor(t1, d);
    m1 = fmaxf(m1, __shfl_xor(m1, d));
  }
  __shared__ float rs[2], rm[2];
  const int lane = k & 63, wid = k >> 6;
  if (lane == 0) { rs[wid] = t1; rm[wid] = m1; }
  __syncthreads();
  if (k == 0) {
    const double LN2 = 0.6931471805599453;
    int Et = ewbuf[b] + ewbuf[BATCH + b];
    out[1 + BATCH + b]     = (float)((double)Et * LN2 + (double)__logf(rs[0] + rs[1]));
    out[1 + 2 * BATCH + b] = fmaxf(rm[0], rm[1]);
  }
}

// ---------------------------------------------------------------------------
// loss = mean(total_score - real_path_score)
// ---------------------------------------------------------------------------
__global__ __launch_bounds__(256, 1)
void crf_loss_kernel(float* __restrict__ out)
{
  const int tid = threadIdx.x;
  float dft = out[1 + BATCH + tid] - out[1 + tid];
#pragma unroll
  for (int d = 1; d <= 32; d <<= 1) dft += __shfl_xor(dft, d);
  __shared__ float rs[4];
  const int lane = tid & 63, wid = tid >> 6;
  if (lane == 0) rs[wid] = dft;
  __syncthreads();
  if (tid == 0)
    out[0] = ((rs[0] + rs[1]) + (rs[2] + rs[3])) * (1.0f / BATCH);
}

extern "C" void kernel_launch(void* const* d_in, const int* in_sizes, int n_in,
                              void* d_out, int out_size, void* d_ws, size_t ws_size,
                              hipStream_t stream)
{
  const float* emis   = (const float*)d_in[0];
  const float* mask   = (const float*)d_in[1];
  const int*   tags   = (const int*)d_in[2];
  const float* trans  = (const float*)d_in[3];
  const float* startt = (const float*)d_in[4];
  const float* stopt  = (const float*)d_in[5];
  float* out = (float*)d_out;

  float* wsf   = (float*)d_ws;                 // 256 * 512 floats
  int*   ewbuf = (int*)(wsf + 512 * BATCH);    // 2 * 256 ints

  crf_fat_kernel<<<5 * BATCH, 512, 0, stream>>>(emis, mask, tags, trans,
                                                startt, stopt, wsf, ewbuf, out);
  crf_combine_kernel<<<BATCH, 128, 0, stream>>>(wsf, ewbuf, out);
  crf_loss_kernel<<<1, 256, 0, stream>>>(out);
}